// Round 6
// baseline (881.273 us; speedup 1.0000x reference)
//
#include <hip/hip_runtime.h>
#include <cmath>

#define HW 307200        // 480*640
#define NB 8             // batches
#define NBASE 63         // input basis channels (ones channel prepended -> 64)
#define NCH 300          // 1024-px chunks per batch
#define BPARTS 32        // b_gram blocks per batch

// ---- workspace layout (float/int indices; ws >= 2.4GB per harness poison) ----
#define XTY_OFF 0                        // 8 * 64  (atomics)
#define YTY_OFF (NB*64)                  // 8       (atomics)
#define NC_OFF  (YTY_OFF + NB)           // 8       (atomics)
#define ZERO_FLOATS (NC_OFF + NB)        // 528: only this region is memset
#define CHC_OFF ZERO_FLOATS              // int: NB*NCH chunk valid-counts
#define CHB_OFF (CHC_OFF + NB*NCH)       // int: NB*NCH chunk exclusive bases
#define CNT_OFF (CHB_OFF + NB*NCH)       // int: NB totals
#define XTX_OFF (CNT_OFF + NB)           // 8 * 64*64 (written whole by reduce)
#define MP_OFF  (XTX_OFF + NB*64*64)     // 8 * 64*64 (upper-tri M, diag/2, /beta)
#define WV_OFF  (MP_OFF + NB*64*64)      // 8 * 64
#define YC_OFF  (WV_OFF + NB*64)         // NB*HW compacted y (padded)
#define XC_OFF  (YC_OFF + NB*HW)         // NB*63*HW compacted basis rows (padded)

// ---- output layout (floats) ----
#define OUT_W   (NB*HW)                  // weights after logits
#define OUT_VAR (OUT_W + NB*64)          // var after weights
// NOTE: b_gram partials (8*32*4096 = 1.05M floats) staged in out[0..), consumed
// by reduce_kernel BEFORE solve/predvar overwrite out. Stream-ordered.

__device__ __forceinline__ bool finitef(float x) {
    // fast-math-proof isfinite: exponent bits not all ones
    return (__float_as_uint(x) & 0x7f800000u) != 0x7f800000u;
}

// ============================================================
// A0a: per-chunk valid counts + yty/N atomics. Pure streaming read
// of targets (10MB). chunk = 1024 px, thread quad = 4 px.
// ============================================================
__global__ __launch_bounds__(256) void a0_count_kernel(
    const float* __restrict__ targets, float* __restrict__ ws)
{
    __shared__ int wq[4];
    const int t = threadIdx.x, b = blockIdx.y, chunk = blockIdx.x;
    const int wv = t >> 6, l = t & 63;
    const float4 ty = *(const float4*)&targets[(long)b * HW + chunk*1024 + 4*t];
    const bool f0 = finitef(ty.x), f1 = finitef(ty.y);
    const bool f2 = finitef(ty.z), f3 = finitef(ty.w);
    int   cc = (int)f0 + (int)f1 + (int)f2 + (int)f3;
    float yy = 0.f;
    if (f0) yy = fmaf(ty.x, ty.x, yy);
    if (f1) yy = fmaf(ty.y, ty.y, yy);
    if (f2) yy = fmaf(ty.z, ty.z, yy);
    if (f3) yy = fmaf(ty.w, ty.w, yy);
    float nn = (float)cc;
#pragma unroll
    for (int off = 32; off; off >>= 1) {
        cc += __shfl_down(cc, off, 64);
        yy += __shfl_down(yy, off, 64);
        nn += __shfl_down(nn, off, 64);
    }
    if (l == 0) {
        wq[wv] = cc;
        atomicAdd(&ws[YTY_OFF + b], yy);
        atomicAdd(&ws[NC_OFF  + b], nn);
    }
    __syncthreads();
    if (t == 0) {
        int* wsi = (int*)ws;
        wsi[CHC_OFF + b*NCH + chunk] = wq[0] + wq[1] + wq[2] + wq[3];
    }
}

// ============================================================
// A0b: per batch (8 blocks x 64 thr): exclusive scan of the 300 chunk
// counts -> chunk bases + total cnt; zero-pad compacted X/y tails up
// to the next multiple of 64 slots (so b_gram needs no edge guards).
// ============================================================
__global__ __launch_bounds__(64) void a0_scan_kernel(float* __restrict__ ws)
{
    const int b = blockIdx.x, t = threadIdx.x;
    int* wsi = (int*)ws;
    const int* chc = wsi + CHC_OFF + b*NCH;
    int*       chb = wsi + CHB_OFF + b*NCH;
    int base = 0;
    for (int i0 = 0; i0 < NCH; i0 += 64) {
        const int idx = i0 + t;
        const int c = (idx < NCH) ? chc[idx] : 0;
        int inc = c;
#pragma unroll
        for (int off = 1; off < 64; off <<= 1) {
            const int u = __shfl_up(inc, off, 64);
            if (t >= off) inc += u;
        }
        if (idx < NCH) chb[idx] = base + (inc - c);
        base += __shfl(inc, 63, 64);
    }
    if (t == 0) wsi[CNT_OFF + b] = base;
    // pad tail slots [cnt, round64(cnt))
    const int cpad = (base + 63) & ~63;
    const int s = base + t;
    if (s < cpad) {
        ws[YC_OFF + (long)b*HW + s] = 0.f;
        float* xc = ws + XC_OFF + (long)b*NBASE*HW + s;
        for (int r = 0; r < NBASE; r++) xc[(long)r * HW] = 0.f;
    }
}

// ============================================================
// A1: the streaming compaction pass. Block = 1024 contiguous px of one
// batch x ALL 63 planes: 63 x 4KB sequential segments at full occupancy
// (no LDS tile, no compute). Valid pixels (~5%) scatter-write into the
// compacted [ch][slot] matrix + ycomp. Slots: scanned chunk base +
// intra-block ballot bijection (order within a chunk is irrelevant --
// gram sums are permutation-invariant).
// ============================================================
__global__ __launch_bounds__(256) void a1_compact_kernel(
    const float* __restrict__ bases, const float* __restrict__ targets,
    float* __restrict__ ws)
{
    __shared__ int wcs[4];
    const int t = threadIdx.x, b = blockIdx.y, chunk = blockIdx.x;
    const int wv = t >> 6, l = t & 63;
    const int p0 = chunk * 1024;

    const float4 ty = *(const float4*)&targets[(long)b * HW + p0 + 4*t];
    const bool f0 = finitef(ty.x), f1 = finitef(ty.y);
    const bool f2 = finitef(ty.z), f3 = finitef(ty.w);
    const unsigned long long M0 = __ballot(f0), M1 = __ballot(f1);
    const unsigned long long M2 = __ballot(f2), M3 = __ballot(f3);
    const int c0t = __popcll(M0), c1t = __popcll(M1), c2t = __popcll(M2);
    const int wc  = c0t + c1t + c2t + __popcll(M3);
    if (l == 0) wcs[wv] = wc;
    __syncthreads();
    int wbase = 0;
    for (int w = 0; w < 4; ++w) if (w < wv) wbase += wcs[w];

    const int* chbp = (const int*)ws + CHB_OFF + b*NCH;
    const int gb = chbp[chunk] + wbase;           // wave-uniform pieces + s_load
    const unsigned long long low = (1ull << l) - 1ull;
    const int s0 = gb + __popcll(M0 & low);
    const int s1 = gb + c0t + __popcll(M1 & low);
    const int s2 = gb + c0t + c1t + __popcll(M2 & low);
    const int s3 = gb + c0t + c1t + c2t + __popcll(M3 & low);

    float* yc = ws + YC_OFF + (long)b * HW;
    if (f0) yc[s0] = ty.x;
    if (f1) yc[s1] = ty.y;
    if (f2) yc[s2] = ty.z;
    if (f3) yc[s3] = ty.w;

    const float* __restrict__ basesb = bases + (long)b * NBASE * HW + p0 + 4*t;
    float* __restrict__ xcb = ws + XC_OFF + (long)b * NBASE * HW;
#pragma unroll 4
    for (int c = 0; c < NBASE; c++) {
        const float4 v = *(const float4*)&basesb[(long)c * HW];
        float* xr = xcb + (long)c * HW;
        if (f0) xr[s0] = v.x;
        if (f1) xr[s1] = v.y;
        if (f2) xr[s2] = v.z;
        if (f3) xr[s3] = v.w;
    }
}

// ============================================================
// B: dense Gram on the compacted matrix (~15.4K slots/batch -> 240
// slabs of 64). Ones channel synthesized from slot<cnt; tails padded
// by A0b. 8x8 register-tile outer product (as before); per-wave accs
// LDS-reduced; one coalesced 16KB partial per block; Xty via atomics.
// ============================================================
__global__ __launch_bounds__(256) void b_gram_kernel(
    float* __restrict__ ws, float* __restrict__ part)
{
    __shared__ float tile[64*68];
    __shared__ float sy[64];

    const int t  = threadIdx.x, b = blockIdx.y;
    const int wv = t >> 6, l = t & 63;
    const int ti = l >> 3, tj = l & 7;
    const int qq = t & 15, cg = t >> 4;

    float acc[8][8];
#pragma unroll
    for (int i = 0; i < 8; i++)
#pragma unroll
        for (int j = 0; j < 8; j++) acc[i][j] = 0.f;
    float acc_xty = 0.f;

    const int cnt = ((const int*)ws)[CNT_OFF + b];
    const int nslab = (cnt + 63) >> 6;
    const float* __restrict__ ycb = ws + YC_OFF + (long)b * HW;
    const float* __restrict__ xcb = ws + XC_OFF + (long)b * NBASE * HW;

    for (int slab = blockIdx.x; slab < nslab; slab += BPARTS) {
        const int s0 = slab << 6;
        if (t < 64) sy[t] = ycb[s0 + t];
#pragma unroll
        for (int k = 0; k < 4; k++) {
            const int cb = cg + 16*k;
            float4 v;
            if (cb == 0) {
                v.x = (s0 + 4*qq + 0 < cnt) ? 1.f : 0.f;
                v.y = (s0 + 4*qq + 1 < cnt) ? 1.f : 0.f;
                v.z = (s0 + 4*qq + 2 < cnt) ? 1.f : 0.f;
                v.w = (s0 + 4*qq + 3 < cnt) ? 1.f : 0.f;
            } else {
                v = *(const float4*)&xcb[(long)(cb - 1) * HW + s0 + 4*qq];
            }
            tile[(4*qq + 0)*68 + cb] = v.x;
            tile[(4*qq + 1)*68 + cb] = v.y;
            tile[(4*qq + 2)*68 + cb] = v.z;
            tile[(4*qq + 3)*68 + cb] = v.w;
        }
        __syncthreads();
#pragma unroll 2
        for (int pp = 0; pp < 16; ++pp) {
            const int p2 = wv * 16 + pp;
            const float4 r0 = *(const float4*)&tile[p2*68 + 8*ti];
            const float4 r1 = *(const float4*)&tile[p2*68 + 8*ti + 4];
            const float4 c0 = *(const float4*)&tile[p2*68 + 8*tj];
            const float4 c1 = *(const float4*)&tile[p2*68 + 8*tj + 4];
            const float rr[8] = {r0.x,r0.y,r0.z,r0.w,r1.x,r1.y,r1.z,r1.w};
            const float cc[8] = {c0.x,c0.y,c0.z,c0.w,c1.x,c1.y,c1.z,c1.w};
#pragma unroll
            for (int i = 0; i < 8; i++)
#pragma unroll
                for (int j = 0; j < 8; j++)
                    acc[i][j] = fmaf(rr[i], cc[j], acc[i][j]);
            acc_xty = fmaf(sy[p2], tile[p2*68 + l], acc_xty);
        }
        __syncthreads();
    }

    // cross-wave reduce of acc tiles into tile[0..4096)
    for (int w = 0; w < 4; ++w) {
        if (wv == w) {
#pragma unroll
            for (int i = 0; i < 8; i++)
#pragma unroll
                for (int j2 = 0; j2 < 8; j2++) {
                    const int e = (8*ti + i) * 64 + 8*tj + j2;
                    tile[e] = (w == 0) ? acc[i][j2] : tile[e] + acc[i][j2];
                }
        }
        __syncthreads();
    }
    float* __restrict__ pb = part + (long)(b * BPARTS + blockIdx.x) * 4096;
#pragma unroll
    for (int k = 0; k < 4; ++k)
        *(float4*)&pb[t*16 + 4*k] = *(const float4*)&tile[t*16 + 4*k];

    for (int w = 0; w < 4; ++w) {
        if (wv == w) tile[4096 + l] = (w == 0) ? acc_xty : tile[4096 + l] + acc_xty;
        __syncthreads();
    }
    if (t < 64) atomicAdd(&ws[XTY_OFF + b*64 + t], tile[4096 + t]);
}

// ============================================================
// reduce: sum the 32 per-block XtX partials -> ws (coalesced)
// ============================================================
__global__ __launch_bounds__(256) void reduce_kernel(
    const float* __restrict__ part, float* __restrict__ ws)
{
    const int b = blockIdx.y;
    const int e = blockIdx.x * 256 + threadIdx.x;   // grid.x = 16 -> e in [0,4096)
    const float* __restrict__ pb = part + (long)b * BPARTS * 4096 + e;
    float s = 0.f;
#pragma unroll 8
    for (int k = 0; k < BPARTS; ++k)
        s += pb[(long)k * 4096];
    ws[XTX_OFF + b*4096 + e] = s;
}

// ============================================================
// solve: per batch, 64 threads = 1 wave. Cholesky in LDS; explicit
// inverse with W-column in 64 registers; Mp emitted by column.
// ============================================================
__global__ __launch_bounds__(64) void solve_kernel(
    float* __restrict__ ws, float* __restrict__ out)
{
    __shared__ float A[64*65];
    __shared__ float d0[64], dinv_s[64], xty_s[64], wv_s[64];

    const int b = blockIdx.x;
    const int t = threadIdx.x;
    const float* XtX = ws + XTX_OFF + b * 4096;

    for (int e = t; e < 4096; e += 64)
        A[(e >> 6) * 65 + (e & 63)] = XtX[e];
    xty_s[t] = ws[XTY_OFF + b*64 + t];
    const float yty = ws[YTY_OFF + b];
    const float Nc  = ws[NC_OFF  + b];
    __syncthreads();
    d0[t] = A[t*65 + t];
    __syncthreads();

    for (int k = 0; k < 64; k++) {
        const float akk = A[k*65 + k];
        __syncthreads();
        const float dk = sqrtf(akk);
        if (t == k)      A[k*65 + k] = dk;
        else if (t > k)  A[t*65 + k] /= dk;
        __syncthreads();
        if (t > k) {
            const float ltk = A[t*65 + k];
            for (int j = k + 1; j <= t; j++)
                A[t*65 + j] -= ltk * A[j*65 + k];
        }
        __syncthreads();
    }

    dinv_s[t] = 1.f / A[t*65 + t];
    __syncthreads();

    float Wc[64];
#pragma unroll
    for (int i = 0; i < 64; i++) {
        float s0 = (i == t) ? 1.f : 0.f, s1 = 0.f, s2 = 0.f, s3 = 0.f;
        const int nfull = i >> 2;
#pragma unroll
        for (int qd = 0; qd < nfull; qd++) {
            const int j = qd * 4;
            s0 = fmaf(-A[i*65 + j    ], Wc[j    ], s0);
            s1 = fmaf(-A[i*65 + j + 1], Wc[j + 1], s1);
            s2 = fmaf(-A[i*65 + j + 2], Wc[j + 2], s2);
            s3 = fmaf(-A[i*65 + j + 3], Wc[j + 3], s3);
        }
#pragma unroll
        for (int j = nfull * 4; j < i; j++)
            s0 = fmaf(-A[i*65 + j], Wc[j], s0);
        Wc[i] = ((s0 + s1) + (s2 + s3)) * dinv_s[i];
    }
#pragma unroll
    for (int i = 63; i >= 0; i--) {
        float s0 = Wc[i], s1 = 0.f, s2 = 0.f, s3 = 0.f;
        const int j0 = i + 1;
        const int nfull = (64 - j0) >> 2;
#pragma unroll
        for (int qd = 0; qd < nfull; qd++) {
            const int j = j0 + qd * 4;
            s0 = fmaf(-A[(j    )*65 + i], Wc[j    ], s0);
            s1 = fmaf(-A[(j + 1)*65 + i], Wc[j + 1], s1);
            s2 = fmaf(-A[(j + 2)*65 + i], Wc[j + 2], s2);
            s3 = fmaf(-A[(j + 3)*65 + i], Wc[j + 3], s3);
        }
#pragma unroll
        for (int j = j0 + nfull * 4; j < 64; j++)
            s0 = fmaf(-A[j*65 + i], Wc[j], s0);
        Wc[i] = ((s0 + s1) + (s2 + s3)) * dinv_s[i];
    }

    float w0 = 0.f, w1 = 0.f, w2 = 0.f, w3 = 0.f;
#pragma unroll
    for (int j = 0; j < 64; j += 4) {
        w0 = fmaf(Wc[j    ], xty_s[j    ], w0);
        w1 = fmaf(Wc[j + 1], xty_s[j + 1], w1);
        w2 = fmaf(Wc[j + 2], xty_s[j + 2], w2);
        w3 = fmaf(Wc[j + 3], xty_s[j + 3], w3);
    }
    const float wt = (w0 + w1) + (w2 + w3);
    wv_s[t] = wt;
    __syncthreads();

    float qt = 0.f;
#pragma unroll
    for (int j = 0; j < 64; j++) {
        const float x = (j > t) ? A[t*65 + j] : ((j == t) ? d0[t] : A[j*65 + t]);
        qt = fmaf(x, wv_s[j], qt);
    }
    float r1 = wt * xty_s[t];
    float r2 = wt * qt;
#pragma unroll
    for (int off = 32; off; off >>= 1) {
        r1 += __shfl_down(r1, off, 64);
        r2 += __shfl_down(r2, off, 64);
    }
    r1 = __shfl(r1, 0, 64);
    r2 = __shfl(r2, 0, 64);
    const float E_d = yty - 2.f * r1 + r2;

    float beta0 = sqrtf(Nc);
    float beta  = beta0;
    bool  done  = false;
#pragma unroll
    for (int it = 0; it < 5; ++it) {
        const float Tr_d = 64.f / beta;
        const float beta_new = Nc / (E_d + Tr_d);
        const bool conv = fabsf(beta_new / beta0 - 1.f) < 0.02f;
        if (!done) { beta = beta_new; beta0 = beta_new; }
        done = done || conv;
    }
    const float ib = 1.f / beta;

    out[OUT_W + b*64 + t] = wt;
    ws[WV_OFF + b*64 + t] = wt;
    float* __restrict__ Mp = ws + MP_OFF + b * 4096;
#pragma unroll
    for (int j = 0; j < 64; j++) {
        const float v = (j > t) ? 0.f : ((j == t) ? 0.5f : 1.f) * Wc[j] * ib;
        Mp[j*64 + t] = v;
    }
}

// ============================================================
// predvar: 2 px/thread. DUAL-PIPE M delivery: even rows via LDS
// broadcast (ds_read_b128), odd rows via wave-uniform GLOBAL reads
// (compiler scalarizes -> s_load, K$ pipe) -- halves the per-wave
// load on each delivery pipe and runs them in parallel with VALU.
// ============================================================
__global__ __launch_bounds__(256, 2) void predvar_kernel(
    const float* __restrict__ bases, const float* __restrict__ ws,
    float* __restrict__ out)
{
    __shared__ float Mp_s[4096];
    __shared__ float w_s[64];

    const int b = blockIdx.y;
    const int t = threadIdx.x;
    const float* __restrict__ Mpg = ws + MP_OFF + b * 4096;
    {
        const float4* __restrict__ src = (const float4*)Mpg;
        float4* dst = (float4*)Mp_s;
        for (int e = t; e < 1024; e += 256) dst[e] = src[e];
        if (t < 64) w_s[t] = ws[WV_OFF + b*64 + t];
    }
    __syncthreads();

    const int pix = (blockIdx.x * 256 + t) * 2;
    const float* basesb = bases + (long)b * NBASE * HW + pix;

    float2 bv[64];
    bv[0] = make_float2(1.f, 1.f);
#pragma unroll
    for (int c = 1; c < 64; c++)
        bv[c] = *(const float2*)&basesb[(long)(c - 1) * HW];

    float px = w_s[0], py = w_s[0];
#pragma unroll
    for (int c = 1; c < 64; c++) {
        px = fmaf(w_s[c], bv[c].x, px);
        py = fmaf(w_s[c], bv[c].y, py);
    }

    float vx = 0.f, vy = 0.f;
#pragma unroll
    for (int i = 0; i < 64; i++) {
        float sx = 0.f, sy2 = 0.f;
#pragma unroll
        for (int qd = i >> 2; qd < 16; qd++) {
            float4 m;
            if (i & 1) m = *(const float4*)&Mpg[i*64 + 4*qd];   // scalar path
            else       m = *(const float4*)&Mp_s[i*64 + 4*qd];  // LDS broadcast
            sx  = fmaf(m.x, bv[4*qd+0].x, sx);
            sy2 = fmaf(m.x, bv[4*qd+0].y, sy2);
            sx  = fmaf(m.y, bv[4*qd+1].x, sx);
            sy2 = fmaf(m.y, bv[4*qd+1].y, sy2);
            sx  = fmaf(m.z, bv[4*qd+2].x, sx);
            sy2 = fmaf(m.z, bv[4*qd+2].y, sy2);
            sx  = fmaf(m.w, bv[4*qd+3].x, sx);
            sy2 = fmaf(m.w, bv[4*qd+3].y, sy2);
        }
        vx = fmaf(sx,  bv[i].x, vx);
        vy = fmaf(sy2, bv[i].y, vy);
    }

    *(float2*)&out[(long)b * HW + pix] = make_float2(px, py);
    *(float2*)&out[OUT_VAR + (long)b * HW + pix] = make_float2(2.f * vx, 2.f * vy);
}

extern "C" void kernel_launch(void* const* d_in, const int* in_sizes, int n_in,
                              void* d_out, int out_size, void* d_ws, size_t ws_size,
                              hipStream_t stream)
{
    const float* bases   = (const float*)d_in[0];
    const float* targets = (const float*)d_in[1];
    float* out = (float*)d_out;
    float* ws  = (float*)d_ws;

    // zero only the atomic-accumulated region (Xty/yty/N)
    hipMemsetAsync(d_ws, 0, ZERO_FLOATS * sizeof(float), stream);

    a0_count_kernel<<<dim3(NCH, NB), 256, 0, stream>>>(targets, ws);
    a0_scan_kernel<<<NB, 64, 0, stream>>>(ws);
    a1_compact_kernel<<<dim3(NCH, NB), 256, 0, stream>>>(bases, targets, ws);
    // XtX partials staged in out[] (dead until reduce consumes them)
    b_gram_kernel<<<dim3(BPARTS, NB), 256, 0, stream>>>(ws, out);
    reduce_kernel<<<dim3(16, NB), 256, 0, stream>>>(out, ws);
    solve_kernel<<<NB, 64, 0, stream>>>(ws, out);
    predvar_kernel<<<dim3(HW / 512, NB), 256, 0, stream>>>(bases, ws, out);
}

// Round 7
// 665.549 us; speedup vs baseline: 1.3241x; 1.3241x over previous
//
#include <hip/hip_runtime.h>
#include <cmath>

#define HW 307200        // 480*640
#define NB 8             // batches
#define NBASE 63         // input basis channels (ones channel prepended -> 64)
#define NCHUNK (HW/256)  // 1200 pixel chunks of 256
#define GRAM_BLKS 128    // gram blocks per batch
#define QCAP 320         // valid-pixel queue capacity (max 63 leftover + 256 new)

// ---- workspace layout (floats) ----
#define XTY_OFF 0                        // 8 * 64
#define YTY_OFF (NB*64)                  // 8
#define NC_OFF  (YTY_OFF + NB)           // 8
#define ZERO_FLOATS (NC_OFF + NB)        // atomic-accumulated region ends here (528)
#define XTX_OFF ZERO_FLOATS              // 8 * 64*64 (written whole by reduce_kernel)
#define MP_OFF  (XTX_OFF + NB*64*64)     // 8 * 64*64 (upper-tri M, diag halved, /beta)
#define WV_OFF  (MP_OFF + NB*64*64)      // 8 * 64

// ---- output layout (floats) ----
#define OUT_W   (NB*HW)                  // weights after logits
#define OUT_VAR (OUT_W + NB*64)          // var after weights
// NOTE: gram partials (8*128*4096 = 16.8MB) are staged in out[], consumed by
// reduce_kernel BEFORE solve/predvar overwrite out. Stream-ordered.

__device__ __forceinline__ bool finitef(float x) {
    // fast-math-proof isfinite: exponent bits not all ones
    return (__float_as_uint(x) & 0x7f800000u) != 0x7f800000u;
}

// ============================================================
// Kernel 1 (measured 245us, best-known): sparse masked Gram.
// Scan targets coalesced, compact valid {pixel,y} into an LDS queue,
// per 64 queued pixels gather the 63 basis channels (lane = channel ->
// conflict-free LDS writes) and run the 8x8 register-tile outer product.
// Per-wave accs LDS-reduced; one coalesced 16KB partial per block.
// ============================================================
__global__ __launch_bounds__(256) void gram_kernel(
    const float* __restrict__ bases, const float* __restrict__ targets,
    float* __restrict__ ws, float* __restrict__ part)
{
    __shared__ float tile[64*68];   // [pixel][channel], stride 68; tail reused for Xty reduce
    __shared__ float sy[64];
    __shared__ float qy[QCAP];
    __shared__ int   qidx[QCAP];
    __shared__ int   qn;

    const int t  = threadIdx.x;
    const int b  = blockIdx.y;
    const int wv = t >> 6;          // wave id 0..3
    const int l  = t & 63;          // lane
    const int ti = l >> 3, tj = l & 7;

    float acc[8][8];
#pragma unroll
    for (int i = 0; i < 8; i++)
#pragma unroll
        for (int j = 0; j < 8; j++) acc[i][j] = 0.f;
    float acc_xty = 0.f, acc_yty = 0.f, acc_n = 0.f;

    const float* __restrict__ basesb = bases + (long)b * NBASE * HW;
    const float* __restrict__ targb  = targets + (long)b * HW;
    const long choff = (long)(l - 1) * HW;   // this lane's channel plane (lane 0 = ones)

    if (t == 0) qn = 0;
    __syncthreads();

    auto compute_tile = [&]() {
#pragma unroll 2
        for (int pp = 0; pp < 16; ++pp) {
            const int p2 = wv * 16 + pp;
            const float4 r0 = *(const float4*)&tile[p2*68 + 8*ti];
            const float4 r1 = *(const float4*)&tile[p2*68 + 8*ti + 4];
            const float4 c0 = *(const float4*)&tile[p2*68 + 8*tj];
            const float4 c1 = *(const float4*)&tile[p2*68 + 8*tj + 4];
            const float rr[8] = {r0.x,r0.y,r0.z,r0.w,r1.x,r1.y,r1.z,r1.w};
            const float cc[8] = {c0.x,c0.y,c0.z,c0.w,c1.x,c1.y,c1.z,c1.w};
#pragma unroll
            for (int i = 0; i < 8; i++)
#pragma unroll
                for (int j = 0; j < 8; j++)
                    acc[i][j] = fmaf(rr[i], cc[j], acc[i][j]);
            // Xty: lane l owns channel l
            acc_xty = fmaf(sy[p2], tile[p2*68 + l], acc_xty);
        }
    };

    int qtot = 0;
    for (int j = blockIdx.x; j < NCHUNK; j += GRAM_BLKS) {
        // ---- append phase: coalesced target read, ballot-compact valid pixels ----
        const int p = j * 256 + t;
        const float y = targb[p];
        const bool fin = finitef(y);
        const unsigned long long m = __ballot(fin);
        int wbase = 0;
        if (l == 0) wbase = atomicAdd(&qn, __popcll(m));
        wbase = __shfl(wbase, 0, 64);
        if (fin) {
            const int r = __popcll(m & ((1ull << l) - 1ull));
            qidx[wbase + r] = p;
            qy[wbase + r]   = y;
            acc_yty = fmaf(y, y, acc_yty);
            acc_n += 1.f;
        }
        __syncthreads();
        qtot = qn;
        // ---- drain phase: gather + Gram per full 64-pixel tile (stack order) ----
        while (qtot >= 64) {
            const int base = qtot - 64;
            if (t < 64) sy[t] = qy[base + t];
#pragma unroll
            for (int pp = wv; pp < 64; pp += 4) {   // 16 independent gathers/thread
                const int gp = qidx[base + pp];     // LDS broadcast
                float v;
                if (l == 0) v = 1.f;                // ones channel (valid pixel)
                else        v = basesb[choff + gp];
                tile[pp*68 + l] = v;                // lane-contiguous: conflict-free
            }
            __syncthreads();
            compute_tile();
            qtot -= 64;
            __syncthreads();
        }
        if (t == 0) qn = qtot;
        __syncthreads();
    }

    // ---- flush remainder (<64 pixels) with zero padding ----
    if (qtot > 0) {
        if (t < 64) sy[t] = (t < qtot) ? qy[t] : 0.f;
#pragma unroll
        for (int pp = wv; pp < 64; pp += 4) {
            float v = 0.f;
            if (pp < qtot) {
                const int gp = qidx[pp];
                if (l == 0) v = 1.f;
                else        v = basesb[choff + gp];
            }
            tile[pp*68 + l] = v;
        }
        __syncthreads();
        compute_tile();
    }
    __syncthreads();

    // ---- cross-wave reduce of acc tiles into tile[0..4096) ----
    for (int w = 0; w < 4; ++w) {
        if (wv == w) {
#pragma unroll
            for (int i = 0; i < 8; i++)
#pragma unroll
                for (int j2 = 0; j2 < 8; j2++) {
                    const int e = (8*ti + i) * 64 + 8*tj + j2;
                    tile[e] = (w == 0) ? acc[i][j2] : tile[e] + acc[i][j2];
                }
        }
        __syncthreads();
    }
    // one coalesced 16KB partial per block, no atomics
    float* __restrict__ pb = part + (long)(b * GRAM_BLKS + blockIdx.x) * 4096;
#pragma unroll
    for (int k = 0; k < 4; ++k)
        *(float4*)&pb[t*16 + 4*k] = *(const float4*)&tile[t*16 + 4*k];

    // Xty: cross-wave reduce into tile[4096..4160), then 64 atomics/block
    for (int w = 0; w < 4; ++w) {
        if (wv == w) tile[4096 + l] = (w == 0) ? acc_xty : tile[4096 + l] + acc_xty;
        __syncthreads();
    }
    if (t < 64) atomicAdd(&ws[XTY_OFF + b*64 + t], tile[4096 + t]);

    // yty, N: wave shuffle reduce + one atomic per wave
#pragma unroll
    for (int off = 32; off; off >>= 1) {
        acc_yty += __shfl_down(acc_yty, off, 64);
        acc_n   += __shfl_down(acc_n,   off, 64);
    }
    if (l == 0) {
        atomicAdd(&ws[YTY_OFF + b], acc_yty);
        atomicAdd(&ws[NC_OFF  + b], acc_n);
    }
}

// ============================================================
// Kernel 1b: sum the 128 per-block XtX partials -> ws (coalesced)
// ============================================================
__global__ __launch_bounds__(256) void reduce_kernel(
    const float* __restrict__ part, float* __restrict__ ws)
{
    const int b = blockIdx.y;
    const int e = blockIdx.x * 256 + threadIdx.x;   // grid.x = 16 -> e in [0,4096)
    const float* __restrict__ pb = part + (long)b * GRAM_BLKS * 4096 + e;
    float s = 0.f;
#pragma unroll 8
    for (int k = 0; k < GRAM_BLKS; ++k)
        s += pb[(long)k * 4096];
    ws[XTX_OFF + b*4096 + e] = s;
}

// ============================================================
// Kernel 2: per batch, 64 threads = 1 wave. Cholesky in LDS;
// explicit inverse with W-column in 64 registers (static indices);
// one reciprocal per row; Mp emitted by column (coalesced).
// ============================================================
__global__ __launch_bounds__(64) void solve_kernel(
    float* __restrict__ ws, float* __restrict__ out)
{
    __shared__ float A[64*65];
    __shared__ float d0[64], dinv_s[64], xty_s[64], wv_s[64];

    const int b = blockIdx.x;
    const int t = threadIdx.x;
    const float* XtX = ws + XTX_OFF + b * 4096;

    for (int e = t; e < 4096; e += 64)
        A[(e >> 6) * 65 + (e & 63)] = XtX[e];
    xty_s[t] = ws[XTY_OFF + b*64 + t];
    const float yty = ws[YTY_OFF + b];
    const float Nc  = ws[NC_OFF  + b];
    __syncthreads();
    d0[t] = A[t*65 + t];
    __syncthreads();

    // Cholesky (lower), upper triangle keeps original XtX
    for (int k = 0; k < 64; k++) {
        const float akk = A[k*65 + k];
        __syncthreads();
        const float dk = sqrtf(akk);
        if (t == k)      A[k*65 + k] = dk;
        else if (t > k)  A[t*65 + k] /= dk;
        __syncthreads();
        if (t > k) {
            const float ltk = A[t*65 + k];
            for (int j = k + 1; j <= t; j++)
                A[t*65 + j] -= ltk * A[j*65 + k];
        }
        __syncthreads();
    }

    dinv_s[t] = 1.f / A[t*65 + t];
    __syncthreads();

    // W = (L L^T)^-1, column t in registers
    float Wc[64];
#pragma unroll
    for (int i = 0; i < 64; i++) {
        float s0 = (i == t) ? 1.f : 0.f, s1 = 0.f, s2 = 0.f, s3 = 0.f;
        const int nfull = i >> 2;
#pragma unroll
        for (int qd = 0; qd < nfull; qd++) {
            const int j = qd * 4;
            s0 = fmaf(-A[i*65 + j    ], Wc[j    ], s0);
            s1 = fmaf(-A[i*65 + j + 1], Wc[j + 1], s1);
            s2 = fmaf(-A[i*65 + j + 2], Wc[j + 2], s2);
            s3 = fmaf(-A[i*65 + j + 3], Wc[j + 3], s3);
        }
#pragma unroll
        for (int j = nfull * 4; j < i; j++)
            s0 = fmaf(-A[i*65 + j], Wc[j], s0);
        Wc[i] = ((s0 + s1) + (s2 + s3)) * dinv_s[i];
    }
#pragma unroll
    for (int i = 63; i >= 0; i--) {
        float s0 = Wc[i], s1 = 0.f, s2 = 0.f, s3 = 0.f;
        const int j0 = i + 1;
        const int nfull = (64 - j0) >> 2;
#pragma unroll
        for (int qd = 0; qd < nfull; qd++) {
            const int j = j0 + qd * 4;
            s0 = fmaf(-A[(j    )*65 + i], Wc[j    ], s0);
            s1 = fmaf(-A[(j + 1)*65 + i], Wc[j + 1], s1);
            s2 = fmaf(-A[(j + 2)*65 + i], Wc[j + 2], s2);
            s3 = fmaf(-A[(j + 3)*65 + i], Wc[j + 3], s3);
        }
#pragma unroll
        for (int j = j0 + nfull * 4; j < 64; j++)
            s0 = fmaf(-A[j*65 + i], Wc[j], s0);
        Wc[i] = ((s0 + s1) + (s2 + s3)) * dinv_s[i];
    }

    // w_t = sum_j W[j][t] * xty[j]  (W symmetric)
    float w0 = 0.f, w1 = 0.f, w2 = 0.f, w3 = 0.f;
#pragma unroll
    for (int j = 0; j < 64; j += 4) {
        w0 = fmaf(Wc[j    ], xty_s[j    ], w0);
        w1 = fmaf(Wc[j + 1], xty_s[j + 1], w1);
        w2 = fmaf(Wc[j + 2], xty_s[j + 2], w2);
        w3 = fmaf(Wc[j + 3], xty_s[j + 3], w3);
    }
    const float wt = (w0 + w1) + (w2 + w3);
    wv_s[t] = wt;
    __syncthreads();

    // E_d = yty - 2 w.Xty + w.(XtX w)  (XtX from upper triangle + saved diag)
    float qt = 0.f;
#pragma unroll
    for (int j = 0; j < 64; j++) {
        const float x = (j > t) ? A[t*65 + j] : ((j == t) ? d0[t] : A[j*65 + t]);
        qt = fmaf(x, wv_s[j], qt);
    }
    float r1 = wt * xty_s[t];
    float r2 = wt * qt;
#pragma unroll
    for (int off = 32; off; off >>= 1) {
        r1 += __shfl_down(r1, off, 64);
        r2 += __shfl_down(r2, off, 64);
    }
    r1 = __shfl(r1, 0, 64);
    r2 = __shfl(r2, 0, 64);
    const float E_d = yty - 2.f * r1 + r2;

    // EM beta loop (uniform on all lanes), faithful to reference latch order
    float beta0 = sqrtf(Nc);
    float beta  = beta0;
    bool  done  = false;
#pragma unroll
    for (int it = 0; it < 5; ++it) {
        const float Tr_d = 64.f / beta;
        const float beta_new = Nc / (E_d + Tr_d);
        const bool conv = fabsf(beta_new / beta0 - 1.f) < 0.02f;
        if (!done) { beta = beta_new; beta0 = beta_new; }
        done = done || conv;
    }
    const float ib = 1.f / beta;

    out[OUT_W + b*64 + t] = wt;
    ws[WV_OFF + b*64 + t] = wt;
    // Mp[row j][col t]: zero below diag, 0.5x diag, * 1/beta. Coalesced column write.
    float* __restrict__ Mp = ws + MP_OFF + b * 4096;
#pragma unroll
    for (int j = 0; j < 64; j++) {
        const float v = (j > t) ? 0.f : ((j == t) ? 0.5f : 1.f) * Wc[j] * ib;
        Mp[j*64 + t] = v;
    }
}

// ============================================================
// Kernel 3: 4 pixels/thread. predvar is LDS-INSTRUCTION-bound:
// the 544 ds_read_b128 of M per wave are a fixed per-wave cost on the
// one LDS pipe per CU (~12cyc each). 4 px/thread halves wave count vs
// 2 px -> halves total LDS-pipe cycles (204us -> ~102us) while VALU
// (~74us) and HBM (~100us) floors stay. bv float4[64] = 256 VGPRs,
// static indices only; __launch_bounds__(256) (no min-wave arg) allows
// the ~300-VGPR allocation without spill (1 wave/SIMD).
// ============================================================
__global__ __launch_bounds__(256) void predvar_kernel(
    const float* __restrict__ bases, const float* __restrict__ ws,
    float* __restrict__ out)
{
    __shared__ float Mp_s[4096];
    __shared__ float w_s[64];

    const int b = blockIdx.y;
    const int t = threadIdx.x;
    {
        const float4* __restrict__ src = (const float4*)(ws + MP_OFF + b * 4096);
        float4* dst = (float4*)Mp_s;
        for (int e = t; e < 1024; e += 256) dst[e] = src[e];
        if (t < 64) w_s[t] = ws[WV_OFF + b*64 + t];
    }
    __syncthreads();

    const int pix = (blockIdx.x * 256 + t) * 4;
    const float* basesb = bases + (long)b * NBASE * HW + pix;

    float4 bv[64];
    bv[0] = make_float4(1.f, 1.f, 1.f, 1.f);
#pragma unroll
    for (int c = 1; c < 64; c++)
        bv[c] = *(const float4*)&basesb[(long)(c - 1) * HW];

    float4 pr = make_float4(w_s[0], w_s[0], w_s[0], w_s[0]);
#pragma unroll
    for (int c = 1; c < 64; c++) {
        pr.x = fmaf(w_s[c], bv[c].x, pr.x);
        pr.y = fmaf(w_s[c], bv[c].y, pr.y);
        pr.z = fmaf(w_s[c], bv[c].z, pr.z);
        pr.w = fmaf(w_s[c], bv[c].w, pr.w);
    }

    float4 vr = make_float4(0.f, 0.f, 0.f, 0.f);
#pragma unroll
    for (int i = 0; i < 64; i++) {
        float4 s = make_float4(0.f, 0.f, 0.f, 0.f);
#pragma unroll
        for (int qd = i >> 2; qd < 16; qd++) {
            const float4 m = *(const float4*)&Mp_s[i*64 + 4*qd];
            s.x = fmaf(m.x, bv[4*qd+0].x, s.x);
            s.y = fmaf(m.x, bv[4*qd+0].y, s.y);
            s.z = fmaf(m.x, bv[4*qd+0].z, s.z);
            s.w = fmaf(m.x, bv[4*qd+0].w, s.w);
            s.x = fmaf(m.y, bv[4*qd+1].x, s.x);
            s.y = fmaf(m.y, bv[4*qd+1].y, s.y);
            s.z = fmaf(m.y, bv[4*qd+1].z, s.z);
            s.w = fmaf(m.y, bv[4*qd+1].w, s.w);
            s.x = fmaf(m.z, bv[4*qd+2].x, s.x);
            s.y = fmaf(m.z, bv[4*qd+2].y, s.y);
            s.z = fmaf(m.z, bv[4*qd+2].z, s.z);
            s.w = fmaf(m.z, bv[4*qd+2].w, s.w);
            s.x = fmaf(m.w, bv[4*qd+3].x, s.x);
            s.y = fmaf(m.w, bv[4*qd+3].y, s.y);
            s.z = fmaf(m.w, bv[4*qd+3].z, s.z);
            s.w = fmaf(m.w, bv[4*qd+3].w, s.w);
        }
        vr.x = fmaf(s.x, bv[i].x, vr.x);
        vr.y = fmaf(s.y, bv[i].y, vr.y);
        vr.z = fmaf(s.z, bv[i].z, vr.z);
        vr.w = fmaf(s.w, bv[i].w, vr.w);
    }

    *(float4*)&out[(long)b * HW + pix] = pr;
    *(float4*)&out[OUT_VAR + (long)b * HW + pix] =
        make_float4(2.f * vr.x, 2.f * vr.y, 2.f * vr.z, 2.f * vr.w);
}

extern "C" void kernel_launch(void* const* d_in, const int* in_sizes, int n_in,
                              void* d_out, int out_size, void* d_ws, size_t ws_size,
                              hipStream_t stream)
{
    const float* bases   = (const float*)d_in[0];
    const float* targets = (const float*)d_in[1];
    float* out = (float*)d_out;
    float* ws  = (float*)d_ws;

    // zero only the atomic-accumulated region (Xty/yty/N); XtX is written whole
    hipMemsetAsync(d_ws, 0, ZERO_FLOATS * sizeof(float), stream);

    // XtX partials staged in out[] (dead until reduce consumes them)
    gram_kernel<<<dim3(GRAM_BLKS, NB), 256, 0, stream>>>(bases, targets, ws, out);
    reduce_kernel<<<dim3(16, NB), 256, 0, stream>>>(out, ws);
    solve_kernel<<<NB, 64, 0, stream>>>(ws, out);
    predvar_kernel<<<dim3(HW / 1024, NB), 256, 0, stream>>>(bases, ws, out);
}